// Round 1
// baseline (4220.997 us; speedup 1.0000x reference)
//
#include <hip/hip_runtime.h>
#include <math.h>

#define IN_DIM 256
#define HID 48
#define CLS 16
#define K_STEPS 10
#define ALPHA 0.1f

// ---------------- small utility kernels ----------------

__global__ void zero_kernel(float* __restrict__ p, int n) {
    int i = blockIdx.x * blockDim.x + threadIdx.x;
    if (i < n) p[i] = 0.0f;
}

__global__ void deg_kernel(const int* __restrict__ dst, float* __restrict__ deg, int nE) {
    int i = blockIdx.x * blockDim.x + threadIdx.x;
    if (i < nE) atomicAdd(&deg[dst[i]], 1.0f);
}

__global__ void norm_kernel(float* __restrict__ deg, int n) {
    int i = blockIdx.x * blockDim.x + threadIdx.x;
    if (i < n) deg[i] = rsqrtf(fmaxf(deg[i], 1.0f));
}

// ---------------- fc1: [n,256] @ [48,256]^T + b1 -> h0 [n,48]; also zeros agg ----------------
// W1 staged transposed in LDS (wT[k][j], conflict-light reads), 8 feature rows
// staged per pass. Each block loops over node chunks (grid-stride by chunk).

#define FC1_NODES 8
__global__ __launch_bounds__(256) void fc1_kernel(
    const float* __restrict__ X, const float* __restrict__ W1,
    const float* __restrict__ b1, float* __restrict__ h0,
    float* __restrict__ agg, int n)
{
    __shared__ float wT[IN_DIM * HID];          // 49152 B, [k][j]
    __shared__ float xs[FC1_NODES * IN_DIM];    // 8192 B
    const int t = threadIdx.x;

    // load W1 transposed (coalesced global read over k)
    for (int i = t; i < IN_DIM * HID; i += 256) {
        int j = i / IN_DIM, k = i % IN_DIM;
        wT[k * HID + j] = W1[i];
    }

    for (int base = blockIdx.x * FC1_NODES; base < n; base += gridDim.x * FC1_NODES) {
        int cnt = min(FC1_NODES, n - base);
        __syncthreads();    // protect xs from previous pass readers (also orders wT load)
        for (int i = t; i < cnt * IN_DIM; i += 256)
            xs[i] = X[base * IN_DIM + i];
        __syncthreads();
        #pragma unroll
        for (int p = 0; p < (FC1_NODES * HID + 255) / 256; p++) {
            int o = t + p * 256;            // output index within chunk
            int ln = o / HID, j = o % HID;
            if (o < FC1_NODES * HID && ln < cnt) {
                float acc = b1[j];
                #pragma unroll 16
                for (int k = 0; k < IN_DIM; k++)
                    acc = fmaf(xs[ln * IN_DIM + k], wT[k * HID + j], acc);
                int idx = (base + ln) * HID + j;
                h0[idx] = acc;
                agg[idx] = 0.0f;
            }
        }
    }
}

// ---------------- fc2 + ELU: [n,48] @ [16,48]^T + b2 -> x0 [n,16] ----------------

__global__ void fc2_kernel(const float* __restrict__ h, const float* __restrict__ W2,
                           const float* __restrict__ b2, float* __restrict__ x0, int n)
{
    int i = blockIdx.x * blockDim.x + threadIdx.x;
    if (i >= n * CLS) return;
    int v = i / CLS, c = i % CLS;
    const float* hr = h + v * HID;
    const float* w  = W2 + c * HID;
    float acc = b2[c];
    #pragma unroll
    for (int d = 0; d < HID; d++) acc = fmaf(hr[d], w[d], acc);
    x0[i] = acc > 0.0f ? acc : expm1f(acc);
}

// ---------------- propagation: push-scatter with atomics ----------------
// block = (D, EPB); one edge per threadIdx.y row; 48 (or 16) lanes cover D.

template<int D, int EPB>
__global__ void scatter_kernel(const float* __restrict__ cur, const float* __restrict__ nrm,
                               const int* __restrict__ src, const int* __restrict__ dst,
                               float* __restrict__ agg, int nE)
{
    int e = blockIdx.x * EPB + threadIdx.y;
    if (e >= nE) return;
    int s = src[e], t = dst[e];
    float v = cur[s * D + threadIdx.x] * nrm[s];
    atomicAdd(&agg[t * D + threadIdx.x], v);
}

// combine: h = 0.9*agg*norm + 0.1*h0 ; re-zero agg for next step.
template<int D, bool FINAL_ELU>
__global__ void combine_kernel(float* __restrict__ h, float* __restrict__ agg,
                               const float* __restrict__ h0, const float* __restrict__ nrm,
                               float* __restrict__ out, int n)
{
    int i = blockIdx.x * blockDim.x + threadIdx.x;
    if (i >= n * D) return;
    int v = i / D;
    float a = agg[i];
    agg[i] = 0.0f;
    float r = (1.0f - ALPHA) * a * nrm[v] + ALPHA * h0[i];
    if (FINAL_ELU) out[i] = r > 0.0f ? r : expm1f(r);
    else           h[i] = r;
}

// ---------------- launch ----------------

extern "C" void kernel_launch(void* const* d_in, const int* in_sizes, int n_in,
                              void* d_out, int out_size, void* d_ws, size_t ws_size,
                              hipStream_t stream)
{
    const float* features = (const float*)d_in[0];
    const int*   src      = (const int*)d_in[1];
    const int*   dst      = (const int*)d_in[2];
    const float* W1       = (const float*)d_in[3];
    const float* b1       = (const float*)d_in[4];
    const float* W2       = (const float*)d_in[5];
    const float* b2       = (const float*)d_in[6];
    float* out = (float*)d_out;

    const int n  = in_sizes[0] / IN_DIM;   // 100000
    const int nE = in_sizes[1];            // 1600000

    // workspace layout (floats): norm[n] | h0[48n] | h[48n] | agg[48n]
    float* ws   = (float*)d_ws;
    float* nrm  = ws;
    float* h0   = nrm + n;
    float* h    = h0 + (size_t)HID * n;
    float* agg  = h  + (size_t)HID * n;
    // stage 2 reuses: x0 = h0 region, x = h region, agg2 = agg region (already zeroed)
    float* x0 = h0;
    float* x  = h;

    const int B = 256;

    // degree -> norm
    zero_kernel<<<(n + B - 1) / B, B, 0, stream>>>(nrm, n);
    deg_kernel<<<(nE + B - 1) / B, B, 0, stream>>>(dst, nrm, nE);
    norm_kernel<<<(n + B - 1) / B, B, 0, stream>>>(nrm, n);

    // fc1 (also zeros agg[0 .. 48n))
    fc1_kernel<<<1024, 256, 0, stream>>>(features, W1, b1, h0, agg, n);

    // propagation 1: D=48
    {
        const int EPB = 8;
        dim3 blk(HID, EPB);
        int grid = (nE + EPB - 1) / EPB;
        int cgrid = (n * HID + B - 1) / B;
        for (int k = 0; k < K_STEPS; k++) {
            const float* cur = (k == 0) ? h0 : h;
            scatter_kernel<HID, EPB><<<grid, blk, 0, stream>>>(cur, nrm, src, dst, agg, nE);
            combine_kernel<HID, false><<<cgrid, B, 0, stream>>>(h, agg, h0, nrm, nullptr, n);
        }
    }

    // fc2 + ELU -> x0 (h0 region; prop1's h0 is dead now)
    fc2_kernel<<<(n * CLS + B - 1) / B, B, 0, stream>>>(h, W2, b2, x0, n);

    // propagation 2: D=16 (agg region first 16n floats already zeroed by combine)
    {
        const int EPB = 16;
        dim3 blk(CLS, EPB);
        int grid = (nE + EPB - 1) / EPB;
        int cgrid = (n * CLS + B - 1) / B;
        for (int k = 0; k < K_STEPS; k++) {
            const float* cur = (k == 0) ? x0 : x;
            scatter_kernel<CLS, EPB><<<grid, blk, 0, stream>>>(cur, nrm, src, dst, agg, nE);
            if (k < K_STEPS - 1)
                combine_kernel<CLS, false><<<cgrid, B, 0, stream>>>(x, agg, x0, nrm, nullptr, n);
            else
                combine_kernel<CLS, true><<<cgrid, B, 0, stream>>>(x, agg, x0, nrm, out, n);
        }
    }
}

// Round 2
// 1689.916 us; speedup vs baseline: 2.4978x; 2.4978x over previous
//
#include <hip/hip_runtime.h>
#include <math.h>

#define IN_DIM 256
#define HID 48
#define CLS 16
#define K_STEPS 10
#define ALPHA 0.1f

// ---------------- utility ----------------

__global__ void zero_int_kernel(int* __restrict__ p, int n) {
    int i = blockIdx.x * blockDim.x + threadIdx.x;
    if (i < n) p[i] = 0;
}

__global__ void hist_kernel(const int* __restrict__ dst, int* __restrict__ deg, int nE) {
    int i = blockIdx.x * blockDim.x + threadIdx.x;
    if (i < nE) atomicAdd(&deg[dst[i]], 1);
}

__global__ void norm_kernel(const int* __restrict__ deg, float* __restrict__ nrm, int n) {
    int i = blockIdx.x * blockDim.x + threadIdx.x;
    if (i < n) nrm[i] = rsqrtf(fmaxf((float)deg[i], 1.0f));
}

// ---------------- exclusive scan over deg -> off, cursor ----------------
// 1024 elements per block (256 threads x 4).

__global__ __launch_bounds__(256) void scan1_kernel(const int* __restrict__ deg,
                                                    int* __restrict__ bsum, int n) {
    __shared__ int ls[256];
    int t = threadIdx.x;
    int base = blockIdx.x * 1024 + t * 4;
    int s = 0;
    if (base + 3 < n) {
        int4 d = *(const int4*)(deg + base);
        s = d.x + d.y + d.z + d.w;
    } else {
        for (int i = 0; i < 4; i++) if (base + i < n) s += deg[base + i];
    }
    ls[t] = s; __syncthreads();
    for (int o = 128; o > 0; o >>= 1) {
        if (t < o) ls[t] += ls[t + o];
        __syncthreads();
    }
    if (t == 0) bsum[blockIdx.x] = ls[0];
}

__global__ void scan2_kernel(int* __restrict__ bsum, int* __restrict__ off, int nb, int n) {
    if (threadIdx.x == 0 && blockIdx.x == 0) {
        int run = 0;
        for (int i = 0; i < nb; i++) { int t = bsum[i]; bsum[i] = run; run += t; }
        off[n] = run;
    }
}

__global__ __launch_bounds__(256) void scan3_kernel(const int* __restrict__ deg,
                                                    const int* __restrict__ bsum,
                                                    int* __restrict__ off,
                                                    int* __restrict__ cursor, int n) {
    __shared__ int ts[256];
    int t = threadIdx.x;
    int base = blockIdx.x * 1024 + t * 4;
    int d0 = 0, d1 = 0, d2 = 0, d3 = 0;
    if (base + 3 < n) {
        int4 d = *(const int4*)(deg + base);
        d0 = d.x; d1 = d.y; d2 = d.z; d3 = d.w;
    } else {
        if (base     < n) d0 = deg[base];
        if (base + 1 < n) d1 = deg[base + 1];
        if (base + 2 < n) d2 = deg[base + 2];
        if (base + 3 < n) d3 = deg[base + 3];
    }
    int s = d0 + d1 + d2 + d3;
    ts[t] = s; __syncthreads();
    // Hillis-Steele inclusive scan over 256 thread sums
    for (int o = 1; o < 256; o <<= 1) {
        int v = (t >= o) ? ts[t - o] : 0;
        __syncthreads();
        ts[t] += v;
        __syncthreads();
    }
    int ex = ts[t] - s + bsum[blockIdx.x];
    int p0 = ex, p1 = ex + d0, p2 = p1 + d1, p3 = p2 + d2;
    if (base     < n) { off[base]     = p0; cursor[base]     = p0; }
    if (base + 1 < n) { off[base + 1] = p1; cursor[base + 1] = p1; }
    if (base + 2 < n) { off[base + 2] = p2; cursor[base + 2] = p2; }
    if (base + 3 < n) { off[base + 3] = p3; cursor[base + 3] = p3; }
}

__global__ void fill_kernel(const int* __restrict__ src, const int* __restrict__ dst,
                            int* __restrict__ cursor, int* __restrict__ csrc, int nE) {
    int e = blockIdx.x * blockDim.x + threadIdx.x;
    if (e >= nE) return;
    int p = atomicAdd(&cursor[dst[e]], 1);
    csrc[p] = src[e];
}

// ---------------- fc1: [n,256] @ [48,256]^T + b1 -> h0, A = h0*nrm ----------------

#define FC1_NODES 8
__global__ __launch_bounds__(256) void fc1_kernel(
    const float* __restrict__ X, const float* __restrict__ W1,
    const float* __restrict__ b1, const float* __restrict__ nrm,
    float* __restrict__ h0, float* __restrict__ A, int n)
{
    __shared__ float wT[IN_DIM * HID];          // [k][j]
    __shared__ float xs[FC1_NODES * IN_DIM];
    const int t = threadIdx.x;

    for (int i = t; i < IN_DIM * HID; i += 256) {
        int j = i / IN_DIM, k = i % IN_DIM;
        wT[k * HID + j] = W1[i];
    }

    for (int base = blockIdx.x * FC1_NODES; base < n; base += gridDim.x * FC1_NODES) {
        int cnt = min(FC1_NODES, n - base);
        __syncthreads();
        for (int i = t; i < cnt * IN_DIM; i += 256)
            xs[i] = X[(size_t)base * IN_DIM + i];
        __syncthreads();
        #pragma unroll
        for (int p = 0; p < (FC1_NODES * HID + 255) / 256; p++) {
            int o = t + p * 256;
            int ln = o / HID, j = o % HID;
            if (o < FC1_NODES * HID && ln < cnt) {
                float acc = b1[j];
                #pragma unroll 16
                for (int k = 0; k < IN_DIM; k++)
                    acc = fmaf(xs[ln * IN_DIM + k], wT[k * HID + j], acc);
                size_t idx = (size_t)(base + ln) * HID + j;
                h0[idx] = acc;
                A[idx] = acc * nrm[base + ln];
            }
        }
    }
}

// ---------------- fc2 + ELU -> x0, xs = x0*nrm ----------------

__global__ void fc2_kernel(const float* __restrict__ h, const float* __restrict__ W2,
                           const float* __restrict__ b2, const float* __restrict__ nrm,
                           float* __restrict__ x0, float* __restrict__ xs, int n)
{
    int i = blockIdx.x * blockDim.x + threadIdx.x;
    if (i >= n * CLS) return;
    int v = i / CLS, c = i % CLS;
    const float* hr = h + (size_t)v * HID;
    const float* w  = W2 + c * HID;
    float acc = b2[c];
    #pragma unroll
    for (int d = 0; d < HID; d++) acc = fmaf(hr[d], w[d], acc);
    float r = acc > 0.0f ? acc : expm1f(acc);
    x0[i] = r;
    xs[i] = r * nrm[v];
}

// ---------------- pull gather + fused combine ----------------
// MODE 0: write r*nrm (scaled, feeds next step)
// MODE 1: write r (unscaled, feeds fc2)
// MODE 2: write elu(r) to output

template<int D, int ROWS, int MODE>
__global__ void gather_kernel(const int* __restrict__ off, const int* __restrict__ csrc,
                              const float* __restrict__ A, const float* __restrict__ h0,
                              const float* __restrict__ nrm, float* __restrict__ outp, int n)
{
    int v = blockIdx.x * ROWS + threadIdx.y;
    if (v >= n) return;
    int lane = threadIdx.x;
    int s = off[v], e = off[v + 1];
    float acc0 = 0.0f, acc1 = 0.0f;
    int i = s;
    for (; i + 1 < e; i += 2) {
        int u0 = csrc[i], u1 = csrc[i + 1];
        acc0 += A[(size_t)u0 * D + lane];
        acc1 += A[(size_t)u1 * D + lane];
    }
    if (i < e) acc0 += A[(size_t)csrc[i] * D + lane];
    float nv = nrm[v];
    float r = (1.0f - ALPHA) * (acc0 + acc1) * nv + ALPHA * h0[(size_t)v * D + lane];
    size_t o = (size_t)v * D + lane;
    if (MODE == 0)      outp[o] = r * nv;
    else if (MODE == 1) outp[o] = r;
    else                outp[o] = r > 0.0f ? r : expm1f(r);
}

// ---------------- launch ----------------

extern "C" void kernel_launch(void* const* d_in, const int* in_sizes, int n_in,
                              void* d_out, int out_size, void* d_ws, size_t ws_size,
                              hipStream_t stream)
{
    const float* features = (const float*)d_in[0];
    const int*   src      = (const int*)d_in[1];
    const int*   dst      = (const int*)d_in[2];
    const float* W1       = (const float*)d_in[3];
    const float* b1       = (const float*)d_in[4];
    const float* W2       = (const float*)d_in[5];
    const float* b2       = (const float*)d_in[6];
    float* out = (float*)d_out;

    const int n  = in_sizes[0] / IN_DIM;   // 100000
    const int nE = in_sizes[1];            // 1600000

    // workspace layout (4-byte words):
    // floats: nrm[n] | h0[48n] | A[48n] | B[48n]
    // ints:   deg[n] | off[n+4] | cursor[n] | bsum[1024] | csrc[nE]
    float* ws   = (float*)d_ws;
    float* nrm  = ws;
    float* h0   = nrm + n;
    float* Abuf = h0 + (size_t)HID * n;
    float* Bbuf = Abuf + (size_t)HID * n;
    int*   deg    = (int*)(Bbuf + (size_t)HID * n);
    int*   off    = deg + n;
    int*   cursor = off + n + 4;
    int*   bsum   = cursor + n;
    int*   csrc   = bsum + 1024;

    const int B = 256;
    const int nb = (n + 1023) / 1024;     // scan blocks (~98)

    // ---- degree, norm, CSR ----
    zero_int_kernel<<<(n + B - 1) / B, B, 0, stream>>>(deg, n);
    hist_kernel<<<(nE + B - 1) / B, B, 0, stream>>>(dst, deg, nE);
    norm_kernel<<<(n + B - 1) / B, B, 0, stream>>>(deg, nrm, n);
    scan1_kernel<<<nb, 256, 0, stream>>>(deg, bsum, n);
    scan2_kernel<<<1, 64, 0, stream>>>(bsum, off, nb, n);
    scan3_kernel<<<nb, 256, 0, stream>>>(deg, bsum, off, cursor, n);
    fill_kernel<<<(nE + B - 1) / B, B, 0, stream>>>(src, dst, cursor, csrc, nE);

    // ---- fc1 -> h0, A = h0*nrm ----
    fc1_kernel<<<1024, 256, 0, stream>>>(features, W1, b1, nrm, h0, Abuf, n);

    // ---- propagation 1: D=48 ----
    {
        const int ROWS = 8;
        dim3 blk(HID, ROWS);
        int grid = (n + ROWS - 1) / ROWS;
        float* pa = Abuf; float* pb = Bbuf;
        for (int k = 0; k < K_STEPS; k++) {
            if (k < K_STEPS - 1)
                gather_kernel<HID, ROWS, 0><<<grid, blk, 0, stream>>>(off, csrc, pa, h0, nrm, pb, n);
            else
                gather_kernel<HID, ROWS, 1><<<grid, blk, 0, stream>>>(off, csrc, pa, h0, nrm, pb, n);
            float* t = pa; pa = pb; pb = t;
        }
        // final h (unscaled) now in pa

        // ---- fc2 + ELU -> x0 (reuse h0 region), xs -> pb ----
        fc2_kernel<<<(n * CLS + B - 1) / B, B, 0, stream>>>(pa, W2, b2, nrm, h0, pb, n);

        // ---- propagation 2: D=16 ----
        const int ROWS2 = 16;
        dim3 blk2(CLS, ROWS2);
        int grid2 = (n + ROWS2 - 1) / ROWS2;
        float* qa = pb; float* qb = pa;   // qa holds xs
        for (int k = 0; k < K_STEPS; k++) {
            if (k < K_STEPS - 1)
                gather_kernel<CLS, ROWS2, 0><<<grid2, blk2, 0, stream>>>(off, csrc, qa, h0, nrm, qb, n);
            else
                gather_kernel<CLS, ROWS2, 2><<<grid2, blk2, 0, stream>>>(off, csrc, qa, h0, nrm, out, n);
            float* t = qa; qa = qb; qb = t;
        }
    }
}

// Round 3
// 1050.622 us; speedup vs baseline: 4.0176x; 1.6085x over previous
//
#include <hip/hip_runtime.h>
#include <math.h>

#define IN_DIM 256
#define HID 48
#define CLS 16
#define K_STEPS 10
#define ALPHA 0.1f

// ---------------- utility ----------------

__global__ void zero_int_kernel(int* __restrict__ p, int n) {
    int i = blockIdx.x * blockDim.x + threadIdx.x;
    if (i < n) p[i] = 0;
}

__global__ void hist_kernel(const int* __restrict__ dst, int* __restrict__ deg, int nE) {
    int i = blockIdx.x * blockDim.x + threadIdx.x;
    if (i < nE) atomicAdd(&deg[dst[i]], 1);
}

__global__ void norm_kernel(const int* __restrict__ deg, float* __restrict__ nrm, int n) {
    int i = blockIdx.x * blockDim.x + threadIdx.x;
    if (i < n) nrm[i] = rsqrtf(fmaxf((float)deg[i], 1.0f));
}

// ---------------- exclusive scan over deg -> off, cursor ----------------

__global__ __launch_bounds__(256) void scan1_kernel(const int* __restrict__ deg,
                                                    int* __restrict__ bsum, int n) {
    __shared__ int ls[256];
    int t = threadIdx.x;
    int base = blockIdx.x * 1024 + t * 4;
    int s = 0;
    if (base + 3 < n) {
        int4 d = *(const int4*)(deg + base);
        s = d.x + d.y + d.z + d.w;
    } else {
        for (int i = 0; i < 4; i++) if (base + i < n) s += deg[base + i];
    }
    ls[t] = s; __syncthreads();
    for (int o = 128; o > 0; o >>= 1) {
        if (t < o) ls[t] += ls[t + o];
        __syncthreads();
    }
    if (t == 0) bsum[blockIdx.x] = ls[0];
}

__global__ void scan2_kernel(int* __restrict__ bsum, int* __restrict__ off, int nb, int n) {
    if (threadIdx.x == 0 && blockIdx.x == 0) {
        int run = 0;
        for (int i = 0; i < nb; i++) { int t = bsum[i]; bsum[i] = run; run += t; }
        off[n] = run;
    }
}

__global__ __launch_bounds__(256) void scan3_kernel(const int* __restrict__ deg,
                                                    const int* __restrict__ bsum,
                                                    int* __restrict__ off,
                                                    int* __restrict__ cursor, int n) {
    __shared__ int ts[256];
    int t = threadIdx.x;
    int base = blockIdx.x * 1024 + t * 4;
    int d0 = 0, d1 = 0, d2 = 0, d3 = 0;
    if (base + 3 < n) {
        int4 d = *(const int4*)(deg + base);
        d0 = d.x; d1 = d.y; d2 = d.z; d3 = d.w;
    } else {
        if (base     < n) d0 = deg[base];
        if (base + 1 < n) d1 = deg[base + 1];
        if (base + 2 < n) d2 = deg[base + 2];
        if (base + 3 < n) d3 = deg[base + 3];
    }
    int s = d0 + d1 + d2 + d3;
    ts[t] = s; __syncthreads();
    for (int o = 1; o < 256; o <<= 1) {
        int v = (t >= o) ? ts[t - o] : 0;
        __syncthreads();
        ts[t] += v;
        __syncthreads();
    }
    int ex = ts[t] - s + bsum[blockIdx.x];
    int p0 = ex, p1 = ex + d0, p2 = p1 + d1, p3 = p2 + d2;
    if (base     < n) { off[base]     = p0; cursor[base]     = p0; }
    if (base + 1 < n) { off[base + 1] = p1; cursor[base + 1] = p1; }
    if (base + 2 < n) { off[base + 2] = p2; cursor[base + 2] = p2; }
    if (base + 3 < n) { off[base + 3] = p3; cursor[base + 3] = p3; }
}

__global__ void fill_kernel(const int* __restrict__ src, const int* __restrict__ dst,
                            int* __restrict__ cursor, int* __restrict__ csrc, int nE) {
    int e = blockIdx.x * blockDim.x + threadIdx.x;
    if (e >= nE) return;
    int p = atomicAdd(&cursor[dst[e]], 1);
    csrc[p] = src[e];
}

// ---------------- fc1: register-tiled GEMM [n,256]x[256,48] ----------------
// 128 nodes x 48 outputs per block, BK=16. Thread (tx,ty): tx=t&31 owns
// m = tx+32*im (strided -> conflict-free Xs reads); ty=t>>5 owns 6 outputs.

#define BM 128
#define BK 16
__global__ __launch_bounds__(256) void fc1_kernel(
    const float* __restrict__ X, const float* __restrict__ W1,
    const float* __restrict__ b1, const float* __restrict__ nrm,
    float* __restrict__ h0, float* __restrict__ A, int n)
{
    __shared__ float Xs[BK][BM + 1];
    __shared__ float Ws[BK][HID];
    const int t = threadIdx.x;
    const int tx = t & 31;
    const int ty = t >> 5;            // 0..7
    const int mbase = blockIdx.x * BM;
    float acc[4][6] = {{0}};

    for (int k0 = 0; k0 < IN_DIM; k0 += BK) {
        // X tile: 128 x 16 = 512 float4 chunks (4 k each); thread loads 2
        #pragma unroll
        for (int c0 = 0; c0 < 2; c0++) {
            int c = t + c0 * 256;
            int m = c >> 2, kc = (c & 3) << 2;
            int gm = mbase + m;
            float4 xv = make_float4(0.f, 0.f, 0.f, 0.f);
            if (gm < n) xv = *(const float4*)(X + (size_t)gm * IN_DIM + k0 + kc);
            Xs[kc + 0][m] = xv.x; Xs[kc + 1][m] = xv.y;
            Xs[kc + 2][m] = xv.z; Xs[kc + 3][m] = xv.w;
        }
        // W tile: 48 x 16 = 192 float4 chunks
        if (t < 192) {
            int j = t >> 2, kc = (t & 3) << 2;
            float4 wv = *(const float4*)(W1 + (size_t)j * IN_DIM + k0 + kc);
            Ws[kc + 0][j] = wv.x; Ws[kc + 1][j] = wv.y;
            Ws[kc + 2][j] = wv.z; Ws[kc + 3][j] = wv.w;
        }
        __syncthreads();
        #pragma unroll
        for (int k = 0; k < BK; k++) {
            float a[4], b[6];
            #pragma unroll
            for (int im = 0; im < 4; im++) a[im] = Xs[k][tx + 32 * im];
            #pragma unroll
            for (int jn = 0; jn < 6; jn++) b[jn] = Ws[k][ty * 6 + jn];
            #pragma unroll
            for (int im = 0; im < 4; im++)
                #pragma unroll
                for (int jn = 0; jn < 6; jn++)
                    acc[im][jn] = fmaf(a[im], b[jn], acc[im][jn]);
        }
        __syncthreads();
    }

    #pragma unroll
    for (int im = 0; im < 4; im++) {
        int m = mbase + tx + 32 * im;
        if (m < n) {
            float nv = nrm[m];
            #pragma unroll
            for (int jn = 0; jn < 6; jn++) {
                int j = ty * 6 + jn;
                float r = acc[im][jn] + b1[j];
                size_t idx = (size_t)m * HID + j;
                h0[idx] = r;
                A[idx] = r * nv;
            }
        }
    }
}

// ---------------- fc2 + ELU: thread-per-node, W2 in LDS ----------------

__global__ __launch_bounds__(256) void fc2_kernel(
    const float* __restrict__ h, const float* __restrict__ W2,
    const float* __restrict__ b2, const float* __restrict__ nrm,
    float* __restrict__ x0, float* __restrict__ xs, int n)
{
    __shared__ float Ws[CLS * HID];
    __shared__ float bs[CLS];
    const int t = threadIdx.x;
    for (int i = t; i < CLS * HID; i += 256) Ws[i] = W2[i];
    if (t < CLS) bs[t] = b2[t];
    __syncthreads();
    int v = blockIdx.x * 256 + t;
    if (v >= n) return;

    float4 hreg[12];
    const float4* hr = (const float4*)(h + (size_t)v * HID);
    #pragma unroll
    for (int d = 0; d < 12; d++) hreg[d] = hr[d];
    float nv = nrm[v];

    float o0[CLS];
    #pragma unroll
    for (int c = 0; c < CLS; c++) {
        const float4* w = (const float4*)(Ws + c * HID);
        float acc = bs[c];
        #pragma unroll
        for (int d = 0; d < 12; d++) {
            float4 wv = w[d];
            acc = fmaf(hreg[d].x, wv.x, acc);
            acc = fmaf(hreg[d].y, wv.y, acc);
            acc = fmaf(hreg[d].z, wv.z, acc);
            acc = fmaf(hreg[d].w, wv.w, acc);
        }
        o0[c] = acc > 0.0f ? acc : expm1f(acc);
    }
    float4* xo  = (float4*)(x0 + (size_t)v * CLS);
    float4* xso = (float4*)(xs + (size_t)v * CLS);
    #pragma unroll
    for (int c4 = 0; c4 < 4; c4++) {
        float4 a = make_float4(o0[c4*4], o0[c4*4+1], o0[c4*4+2], o0[c4*4+3]);
        xo[c4] = a;
        xso[c4] = make_float4(a.x * nv, a.y * nv, a.z * nv, a.w * nv);
    }
}

// ---------------- pull gather + fused combine (float4) ----------------
// DV = D/4 float4 lanes per node row.
// MODE 0: write r*nrm ; MODE 1: write r ; MODE 2: write elu(r)

__device__ __forceinline__ void f4add(float4& a, const float4& b) {
    a.x += b.x; a.y += b.y; a.z += b.z; a.w += b.w;
}

template<int DV, int ROWS, int MODE>
__global__ __launch_bounds__(DV * ROWS) void gather4_kernel(
    const int* __restrict__ off, const int* __restrict__ csrc,
    const float4* __restrict__ A, const float4* __restrict__ h0,
    const float* __restrict__ nrm, float4* __restrict__ outp, int n)
{
    int v = blockIdx.x * ROWS + threadIdx.y;
    if (v >= n) return;
    int lane = threadIdx.x;
    int s = off[v], e = off[v + 1];
    float4 a0 = make_float4(0.f, 0.f, 0.f, 0.f), a1 = a0;
    int i = s;
    for (; i + 3 < e; i += 4) {
        int u0 = csrc[i], u1 = csrc[i + 1], u2 = csrc[i + 2], u3 = csrc[i + 3];
        float4 v0 = A[(size_t)u0 * DV + lane];
        float4 v1 = A[(size_t)u1 * DV + lane];
        float4 v2 = A[(size_t)u2 * DV + lane];
        float4 v3 = A[(size_t)u3 * DV + lane];
        f4add(a0, v0); f4add(a1, v1); f4add(a0, v2); f4add(a1, v3);
    }
    for (; i < e; i++) f4add(a0, A[(size_t)csrc[i] * DV + lane]);
    f4add(a0, a1);

    float nv = nrm[v];
    float4 hv = h0[(size_t)v * DV + lane];
    float4 r;
    r.x = (1.0f - ALPHA) * a0.x * nv + ALPHA * hv.x;
    r.y = (1.0f - ALPHA) * a0.y * nv + ALPHA * hv.y;
    r.z = (1.0f - ALPHA) * a0.z * nv + ALPHA * hv.z;
    r.w = (1.0f - ALPHA) * a0.w * nv + ALPHA * hv.w;
    if (MODE == 0) { r.x *= nv; r.y *= nv; r.z *= nv; r.w *= nv; }
    if (MODE == 2) {
        r.x = r.x > 0.f ? r.x : expm1f(r.x);
        r.y = r.y > 0.f ? r.y : expm1f(r.y);
        r.z = r.z > 0.f ? r.z : expm1f(r.z);
        r.w = r.w > 0.f ? r.w : expm1f(r.w);
    }
    outp[(size_t)v * DV + lane] = r;
}

// ---------------- launch ----------------

extern "C" void kernel_launch(void* const* d_in, const int* in_sizes, int n_in,
                              void* d_out, int out_size, void* d_ws, size_t ws_size,
                              hipStream_t stream)
{
    const float* features = (const float*)d_in[0];
    const int*   src      = (const int*)d_in[1];
    const int*   dst      = (const int*)d_in[2];
    const float* W1       = (const float*)d_in[3];
    const float* b1       = (const float*)d_in[4];
    const float* W2       = (const float*)d_in[5];
    const float* b2       = (const float*)d_in[6];
    float* out = (float*)d_out;

    const int n  = in_sizes[0] / IN_DIM;   // 100000
    const int nE = in_sizes[1];            // 1600000

    // workspace: floats nrm[n] | h0[48n] | A[48n] | B[48n]
    //            ints   deg[n] | off[n+4] | cursor[n] | bsum[1024] | csrc[nE]
    float* ws   = (float*)d_ws;
    float* nrm  = ws;
    float* h0   = nrm + n;
    float* Abuf = h0 + (size_t)HID * n;
    float* Bbuf = Abuf + (size_t)HID * n;
    int*   deg    = (int*)(Bbuf + (size_t)HID * n);
    int*   off    = deg + n;
    int*   cursor = off + n + 4;
    int*   bsum   = cursor + n;
    int*   csrc   = bsum + 1024;

    const int B = 256;
    const int nb = (n + 1023) / 1024;

    // ---- degree, norm, CSR ----
    zero_int_kernel<<<(n + B - 1) / B, B, 0, stream>>>(deg, n);
    hist_kernel<<<(nE + B - 1) / B, B, 0, stream>>>(dst, deg, nE);
    norm_kernel<<<(n + B - 1) / B, B, 0, stream>>>(deg, nrm, n);
    scan1_kernel<<<nb, 256, 0, stream>>>(deg, bsum, n);
    scan2_kernel<<<1, 64, 0, stream>>>(bsum, off, nb, n);
    scan3_kernel<<<nb, 256, 0, stream>>>(deg, bsum, off, cursor, n);
    fill_kernel<<<(nE + B - 1) / B, B, 0, stream>>>(src, dst, cursor, csrc, nE);

    // ---- fc1 -> h0, A = h0*nrm ----
    fc1_kernel<<<(n + BM - 1) / BM, 256, 0, stream>>>(features, W1, b1, nrm, h0, Abuf, n);

    // ---- propagation 1: D=48 (DV=12) ----
    float* pa = Abuf; float* pb = Bbuf;
    {
        const int ROWS = 32;
        dim3 blk(12, ROWS);
        int grid = (n + ROWS - 1) / ROWS;
        for (int k = 0; k < K_STEPS; k++) {
            if (k < K_STEPS - 1)
                gather4_kernel<12, ROWS, 0><<<grid, blk, 0, stream>>>(
                    off, csrc, (const float4*)pa, (const float4*)h0, nrm, (float4*)pb, n);
            else
                gather4_kernel<12, ROWS, 1><<<grid, blk, 0, stream>>>(
                    off, csrc, (const float4*)pa, (const float4*)h0, nrm, (float4*)pb, n);
            float* t = pa; pa = pb; pb = t;
        }
    }

    // ---- fc2 + ELU -> x0 (h0 region), xs -> pb ----
    fc2_kernel<<<(n + 255) / 256, 256, 0, stream>>>(pa, W2, b2, nrm, h0, pb, n);

    // ---- propagation 2: D=16 (DV=4) ----
    {
        const int ROWS = 32;
        dim3 blk(4, ROWS);
        int grid = (n + ROWS - 1) / ROWS;
        float* qa = pb; float* qb = pa;
        for (int k = 0; k < K_STEPS; k++) {
            if (k < K_STEPS - 1)
                gather4_kernel<4, ROWS, 0><<<grid, blk, 0, stream>>>(
                    off, csrc, (const float4*)qa, (const float4*)h0, nrm, (float4*)qb, n);
            else
                gather4_kernel<4, ROWS, 2><<<grid, blk, 0, stream>>>(
                    off, csrc, (const float4*)qa, (const float4*)h0, nrm, (float4*)out, n);
            float* t = qa; qa = qb; qb = t;
        }
    }
}

// Round 4
// 707.745 us; speedup vs baseline: 5.9640x; 1.4845x over previous
//
#include <hip/hip_runtime.h>
#include <math.h>

#define IN_DIM 256
#define HID 48
#define CLS 16
#define K_STEPS 10
#define ALPHA 0.1f

// ---------------- utility ----------------

__global__ void zero_int_kernel(int* __restrict__ p, int n) {
    int i = blockIdx.x * blockDim.x + threadIdx.x;
    if (i < n) p[i] = 0;
}

__global__ void hist_kernel(const int* __restrict__ dst, int* __restrict__ deg, int nE) {
    int i = blockIdx.x * blockDim.x + threadIdx.x;
    if (i < nE) atomicAdd(&deg[dst[i]], 1);
}

__global__ void norm_kernel(const int* __restrict__ deg, float* __restrict__ nrm, int n) {
    int i = blockIdx.x * blockDim.x + threadIdx.x;
    if (i < n) nrm[i] = rsqrtf(fmaxf((float)deg[i], 1.0f));
}

// ---------------- exclusive scan over deg -> off, cursor ----------------

__global__ __launch_bounds__(256) void scan1_kernel(const int* __restrict__ deg,
                                                    int* __restrict__ bsum, int n) {
    __shared__ int ls[256];
    int t = threadIdx.x;
    int base = blockIdx.x * 1024 + t * 4;
    int s = 0;
    if (base + 3 < n) {
        int4 d = *(const int4*)(deg + base);
        s = d.x + d.y + d.z + d.w;
    } else {
        for (int i = 0; i < 4; i++) if (base + i < n) s += deg[base + i];
    }
    ls[t] = s; __syncthreads();
    for (int o = 128; o > 0; o >>= 1) {
        if (t < o) ls[t] += ls[t + o];
        __syncthreads();
    }
    if (t == 0) bsum[blockIdx.x] = ls[0];
}

__global__ void scan2_kernel(int* __restrict__ bsum, int* __restrict__ off, int nb, int n) {
    if (threadIdx.x == 0 && blockIdx.x == 0) {
        int run = 0;
        for (int i = 0; i < nb; i++) { int t = bsum[i]; bsum[i] = run; run += t; }
        off[n] = run;
    }
}

__global__ __launch_bounds__(256) void scan3_kernel(const int* __restrict__ deg,
                                                    const int* __restrict__ bsum,
                                                    int* __restrict__ off,
                                                    int* __restrict__ cursor, int n) {
    __shared__ int ts[256];
    int t = threadIdx.x;
    int base = blockIdx.x * 1024 + t * 4;
    int d0 = 0, d1 = 0, d2 = 0, d3 = 0;
    if (base + 3 < n) {
        int4 d = *(const int4*)(deg + base);
        d0 = d.x; d1 = d.y; d2 = d.z; d3 = d.w;
    } else {
        if (base     < n) d0 = deg[base];
        if (base + 1 < n) d1 = deg[base + 1];
        if (base + 2 < n) d2 = deg[base + 2];
        if (base + 3 < n) d3 = deg[base + 3];
    }
    int s = d0 + d1 + d2 + d3;
    ts[t] = s; __syncthreads();
    for (int o = 1; o < 256; o <<= 1) {
        int v = (t >= o) ? ts[t - o] : 0;
        __syncthreads();
        ts[t] += v;
        __syncthreads();
    }
    int ex = ts[t] - s + bsum[blockIdx.x];
    int p0 = ex, p1 = ex + d0, p2 = p1 + d1, p3 = p2 + d2;
    if (base     < n) { off[base]     = p0; cursor[base]     = p0; }
    if (base + 1 < n) { off[base + 1] = p1; cursor[base + 1] = p1; }
    if (base + 2 < n) { off[base + 2] = p2; cursor[base + 2] = p2; }
    if (base + 3 < n) { off[base + 3] = p3; cursor[base + 3] = p3; }
}

__global__ void fill_kernel(const int* __restrict__ src, const int* __restrict__ dst,
                            int* __restrict__ cursor, int* __restrict__ csrc, int nE) {
    int e = blockIdx.x * blockDim.x + threadIdx.x;
    if (e >= nE) return;
    int p = atomicAdd(&cursor[dst[e]], 1);
    csrc[p] = src[e];
}

// ---------------- Wc = W2 @ W1 [16,256], bc = W2 @ b1 [16] ----------------

__global__ __launch_bounds__(256) void wc_kernel(
    const float* __restrict__ W1, const float* __restrict__ W2,
    const float* __restrict__ b1, float* __restrict__ Wc, float* __restrict__ bc)
{
    int c = blockIdx.x;         // 0..15
    int k = threadIdx.x;        // 0..255
    float acc = 0.0f;
    #pragma unroll
    for (int j = 0; j < HID; j++)
        acc = fmaf(W2[c * HID + j], W1[j * IN_DIM + k], acc);
    Wc[c * IN_DIM + k] = acc;
    if (k == 0) {
        float b = 0.0f;
        for (int j = 0; j < HID; j++) b = fmaf(W2[c * HID + j], b1[j], b);
        bc[c] = b;
    }
}

// ---------------- fused fc: z0 = X @ Wc^T + bc; A = z0*nrm ----------------
// register-tiled GEMM, 128 nodes x 16 outputs per block, BK=16.

#define BM 128
#define BK 16
__global__ __launch_bounds__(256) void fcz_kernel(
    const float* __restrict__ X, const float* __restrict__ Wc,
    const float* __restrict__ bc, const float* __restrict__ nrm,
    float* __restrict__ z0, float* __restrict__ A, int n)
{
    __shared__ float Xs[BK][BM + 1];
    __shared__ float Ws[BK][CLS];
    const int t = threadIdx.x;
    const int tx = t & 31;
    const int ty = t >> 5;            // 0..7, owns 2 outputs
    const int mbase = blockIdx.x * BM;
    float acc[4][2] = {{0}};

    for (int k0 = 0; k0 < IN_DIM; k0 += BK) {
        #pragma unroll
        for (int c0 = 0; c0 < 2; c0++) {
            int c = t + c0 * 256;
            int m = c >> 2, kc = (c & 3) << 2;
            int gm = mbase + m;
            float4 xv = make_float4(0.f, 0.f, 0.f, 0.f);
            if (gm < n) xv = *(const float4*)(X + (size_t)gm * IN_DIM + k0 + kc);
            Xs[kc + 0][m] = xv.x; Xs[kc + 1][m] = xv.y;
            Xs[kc + 2][m] = xv.z; Xs[kc + 3][m] = xv.w;
        }
        if (t < 64) {
            int j = t >> 2, kc = (t & 3) << 2;
            float4 wv = *(const float4*)(Wc + (size_t)j * IN_DIM + k0 + kc);
            Ws[kc + 0][j] = wv.x; Ws[kc + 1][j] = wv.y;
            Ws[kc + 2][j] = wv.z; Ws[kc + 3][j] = wv.w;
        }
        __syncthreads();
        #pragma unroll
        for (int k = 0; k < BK; k++) {
            float a[4], b[2];
            #pragma unroll
            for (int im = 0; im < 4; im++) a[im] = Xs[k][tx + 32 * im];
            #pragma unroll
            for (int jn = 0; jn < 2; jn++) b[jn] = Ws[k][ty * 2 + jn];
            #pragma unroll
            for (int im = 0; im < 4; im++)
                #pragma unroll
                for (int jn = 0; jn < 2; jn++)
                    acc[im][jn] = fmaf(a[im], b[jn], acc[im][jn]);
        }
        __syncthreads();
    }

    #pragma unroll
    for (int im = 0; im < 4; im++) {
        int m = mbase + tx + 32 * im;
        if (m < n) {
            float nv = nrm[m];
            #pragma unroll
            for (int jn = 0; jn < 2; jn++) {
                int j = ty * 2 + jn;
                float r = acc[im][jn] + bc[j];
                size_t idx = (size_t)m * CLS + j;
                z0[idx] = r;
                A[idx] = r * nv;
            }
        }
    }
}

// ---------------- pull gather + fused combine (D=16, float4) ----------------
// MODE 0: outp = r*nrm (scaled, feeds next step)
// MODE 1: end of prop1: e = elu(r + b2); out2 = e (teleport), outp = e*nrm
// MODE 2: outp = elu(r) (final output)

__device__ __forceinline__ void f4add(float4& a, const float4& b) {
    a.x += b.x; a.y += b.y; a.z += b.z; a.w += b.w;
}
__device__ __forceinline__ float eluf(float x) {
    return x > 0.0f ? x : expm1f(x);
}

template<int ROWS, int MODE>
__global__ __launch_bounds__(4 * ROWS) void gather4_kernel(
    const int* __restrict__ off, const int* __restrict__ csrc,
    const float4* __restrict__ A, const float4* __restrict__ tele,
    const float* __restrict__ nrm, const float4* __restrict__ b2v,
    float4* __restrict__ outp, float4* __restrict__ out2, int n)
{
    int v = blockIdx.x * ROWS + threadIdx.y;
    if (v >= n) return;
    int lane = threadIdx.x;    // 0..3
    int s = off[v], e = off[v + 1];
    float4 a0 = make_float4(0.f, 0.f, 0.f, 0.f), a1 = a0;
    int i = s;
    for (; i + 3 < e; i += 4) {
        int u0 = csrc[i], u1 = csrc[i + 1], u2 = csrc[i + 2], u3 = csrc[i + 3];
        float4 v0 = A[(size_t)u0 * 4 + lane];
        float4 v1 = A[(size_t)u1 * 4 + lane];
        float4 v2 = A[(size_t)u2 * 4 + lane];
        float4 v3 = A[(size_t)u3 * 4 + lane];
        f4add(a0, v0); f4add(a1, v1); f4add(a0, v2); f4add(a1, v3);
    }
    for (; i < e; i++) f4add(a0, A[(size_t)csrc[i] * 4 + lane]);
    f4add(a0, a1);

    float nv = nrm[v];
    size_t o = (size_t)v * 4 + lane;
    float4 hv = tele[o];
    float4 r;
    r.x = (1.0f - ALPHA) * a0.x * nv + ALPHA * hv.x;
    r.y = (1.0f - ALPHA) * a0.y * nv + ALPHA * hv.y;
    r.z = (1.0f - ALPHA) * a0.z * nv + ALPHA * hv.z;
    r.w = (1.0f - ALPHA) * a0.w * nv + ALPHA * hv.w;
    if (MODE == 0) {
        outp[o] = make_float4(r.x * nv, r.y * nv, r.z * nv, r.w * nv);
    } else if (MODE == 1) {
        float4 b = b2v[lane];
        float4 x;
        x.x = eluf(r.x + b.x); x.y = eluf(r.y + b.y);
        x.z = eluf(r.z + b.z); x.w = eluf(r.w + b.w);
        out2[o] = x;
        outp[o] = make_float4(x.x * nv, x.y * nv, x.z * nv, x.w * nv);
    } else {
        outp[o] = make_float4(eluf(r.x), eluf(r.y), eluf(r.z), eluf(r.w));
    }
}

// ---------------- launch ----------------

extern "C" void kernel_launch(void* const* d_in, const int* in_sizes, int n_in,
                              void* d_out, int out_size, void* d_ws, size_t ws_size,
                              hipStream_t stream)
{
    const float* features = (const float*)d_in[0];
    const int*   src      = (const int*)d_in[1];
    const int*   dst      = (const int*)d_in[2];
    const float* W1       = (const float*)d_in[3];
    const float* b1       = (const float*)d_in[4];
    const float* W2       = (const float*)d_in[5];
    const float* b2       = (const float*)d_in[6];
    float* out = (float*)d_out;

    const int n  = in_sizes[0] / IN_DIM;   // 100000
    const int nE = in_sizes[1];            // 1600000

    // workspace: floats nrm[n] | z0[16n] | P[16n] | Q[16n] | x0[16n] | Wc[4096] | bc[16]
    //            ints   deg[n] | off[n+4] | cursor[n] | bsum[1024] | csrc[nE]
    float* ws   = (float*)d_ws;
    float* nrm  = ws;
    float* z0   = nrm + n;
    float* P    = z0 + (size_t)CLS * n;
    float* Q    = P + (size_t)CLS * n;
    float* x0   = Q + (size_t)CLS * n;
    float* Wc   = x0 + (size_t)CLS * n;
    float* bc   = Wc + CLS * IN_DIM;
    int*   deg    = (int*)(bc + 16);
    int*   off    = deg + n;
    int*   cursor = off + n + 4;
    int*   bsum   = cursor + n;
    int*   csrc   = bsum + 1024;

    const int B = 256;
    const int nb = (n + 1023) / 1024;

    // ---- degree, norm, CSR ----
    zero_int_kernel<<<(n + B - 1) / B, B, 0, stream>>>(deg, n);
    hist_kernel<<<(nE + B - 1) / B, B, 0, stream>>>(dst, deg, nE);
    norm_kernel<<<(n + B - 1) / B, B, 0, stream>>>(deg, nrm, n);
    scan1_kernel<<<nb, 256, 0, stream>>>(deg, bsum, n);
    scan2_kernel<<<1, 64, 0, stream>>>(bsum, off, nb, n);
    scan3_kernel<<<nb, 256, 0, stream>>>(deg, bsum, off, cursor, n);
    fill_kernel<<<(nE + B - 1) / B, B, 0, stream>>>(src, dst, cursor, csrc, nE);

    // ---- combined fc: Wc = W2@W1, bc = W2@b1; z0 = X@Wc^T + bc; A = z0*nrm ----
    wc_kernel<<<CLS, 256, 0, stream>>>(W1, W2, b1, Wc, bc);
    fcz_kernel<<<(n + BM - 1) / BM, 256, 0, stream>>>(features, Wc, bc, nrm, z0, P, n);

    const int ROWS = 64;
    dim3 blk(4, ROWS);
    int grid = (n + ROWS - 1) / ROWS;

    // ---- propagation 1 (D=16, teleport z0); last step fuses +b2, ELU ----
    float* pa = P; float* pb = Q;
    for (int k = 0; k < K_STEPS; k++) {
        if (k < K_STEPS - 1)
            gather4_kernel<ROWS, 0><<<grid, blk, 0, stream>>>(
                off, csrc, (const float4*)pa, (const float4*)z0, nrm,
                nullptr, (float4*)pb, nullptr, n);
        else
            gather4_kernel<ROWS, 1><<<grid, blk, 0, stream>>>(
                off, csrc, (const float4*)pa, (const float4*)z0, nrm,
                (const float4*)b2, (float4*)pb, (float4*)x0, n);
        float* t = pa; pa = pb; pb = t;
    }

    // ---- propagation 2 (D=16, teleport x0); last step fuses ELU -> out ----
    for (int k = 0; k < K_STEPS; k++) {
        if (k < K_STEPS - 1)
            gather4_kernel<ROWS, 0><<<grid, blk, 0, stream>>>(
                off, csrc, (const float4*)pa, (const float4*)x0, nrm,
                nullptr, (float4*)pb, nullptr, n);
        else
            gather4_kernel<ROWS, 2><<<grid, blk, 0, stream>>>(
                off, csrc, (const float4*)pa, (const float4*)x0, nrm,
                nullptr, (float4*)out, nullptr, n);
        float* t = pa; pa = pb; pb = t;
    }
}